// Round 1
// baseline (130.633 us; speedup 1.0000x reference)
//
#include <hip/hip_runtime.h>

#define NB 16
#define NA 76725
#define NC 8
#define NM 32
#define FEPS 1e-4f

// ws layout: per image b: [b*4+0]=cls_sum(float), [b*4+1]=reg_sum(float),
//            [b*4+2]=npos(uint), [b*4+3]=pad
__global__ __launch_bounds__(256) void focal_main(
    const float* __restrict__ cls_,
    const float* __restrict__ reg_,
    const float* __restrict__ anch_,
    const float* __restrict__ ann_,
    float* __restrict__ ws)
{
    __shared__ float s_ann[NM * 5];
    const int b   = blockIdx.y;
    const int tid = threadIdx.x;
    if (tid < NM * 5) s_ann[tid] = ann_[(size_t)b * NM * 5 + tid];
    __syncthreads();

    const int a = blockIdx.x * 256 + tid;
    float cls_c = 0.f, reg_c = 0.f;
    unsigned pos_c = 0;

    if (a < NA) {
        const float4 an = *reinterpret_cast<const float4*>(anch_ + ((size_t)b * NA + a) * 4);
        const float area1 = (an.z - an.x + 1.f) * (an.w - an.y + 1.f);

        float ioumax = -1.f;
        int   arg    = 0;
        for (int m = 0; m < NM; ++m) {
            const float x1  = s_ann[m * 5 + 0];
            const float y1  = s_ann[m * 5 + 1];
            const float x2  = s_ann[m * 5 + 2];
            const float y2  = s_ann[m * 5 + 3];
            const float lab = s_ann[m * 5 + 4];
            float iou = -1.f;
            if (lab > -0.5f) {
                const float w = fminf(an.z, x2) - fmaxf(an.x, x1) + 1.f;
                const float h = fminf(an.w, y2) - fmaxf(an.y, y1) + 1.f;
                const float inter = fmaxf(w, 0.f) * fmaxf(h, 0.f);
                const float area2 = (x2 - x1 + 1.f) * (y2 - y1 + 1.f);
                iou = inter / (area1 + area2 - inter);
            }
            if (iou > ioumax) { ioumax = iou; arg = m; }  // strict > == first-occurrence argmax
        }
        const bool pos = (ioumax >= 0.4f);
        const bool neg = (ioumax <  0.3f);

        if (pos || neg) {
            // one-hot class only matters when pos; labi=-1 means "all targets 0"
            const int labi = pos ? (int)s_ann[arg * 5 + 4] : -1;
            const float4 c0 = *reinterpret_cast<const float4*>(cls_ + ((size_t)b * NA + a) * NC);
            const float4 c1 = *reinterpret_cast<const float4*>(cls_ + ((size_t)b * NA + a) * NC + 4);
            const float pv[8] = {c0.x, c0.y, c0.z, c0.w, c1.x, c1.y, c1.z, c1.w};
            #pragma unroll
            for (int c = 0; c < NC; ++c) {
                const float p = fminf(fmaxf(pv[c], FEPS), 1.f - FEPS);
                const bool  is_one = (c == labi);
                const float af  = is_one ? 0.25f : 0.75f;
                const float pf  = is_one ? (1.f - p) : p;
                const float bce = -__logf(is_one ? p : (1.f - p));  // -log(p) / -log1p(-p)
                cls_c += af * pf * pf * bce;
            }
        }
        if (pos) {
            pos_c = 1;
            const float x1 = s_ann[arg * 5 + 0];
            const float y1 = s_ann[arg * 5 + 1];
            const float x2 = s_ann[arg * 5 + 2];
            const float y2 = s_ann[arg * 5 + 3];
            const float aw  = an.z - an.x;            // no +1 for regression geometry
            const float ah  = an.w - an.y;
            const float acx = an.x + 0.5f * aw;
            const float acy = an.y + 0.5f * ah;
            const float w0  = x2 - x1;
            const float h0  = y2 - y1;
            const float gcx = x1 + 0.5f * w0;         // centers from UNCLAMPED w0/h0
            const float gcy = y1 + 0.5f * h0;
            const float gw  = fmaxf(w0, 1.f);         // logs from clamped
            const float gh  = fmaxf(h0, 1.f);
            const float t0 = ((gcx - acx) / aw) * 10.f;   // /0.1
            const float t1 = ((gcy - acy) / ah) * 10.f;
            const float t2 = __logf(gw / aw) * 5.f;       // /0.2
            const float t3 = __logf(gh / ah) * 5.f;
            const float4 rg = *reinterpret_cast<const float4*>(reg_ + ((size_t)b * NA + a) * 4);
            const float d0 = fabsf(t0 - rg.x);
            const float d1 = fabsf(t1 - rg.y);
            const float d2 = fabsf(t2 - rg.z);
            const float d3 = fabsf(t3 - rg.w);
            auto sl1 = [](float d) {
                return d <= (1.f / 9.f) ? 4.5f * d * d : d - (0.5f / 9.f);
            };
            reg_c = sl1(d0) + sl1(d1) + sl1(d2) + sl1(d3);
        }
    }

    // wave-64 shuffle reduction, then cross-wave via LDS, then 3 atomics/block
    #pragma unroll
    for (int off = 32; off > 0; off >>= 1) {
        cls_c += __shfl_down(cls_c, off);
        reg_c += __shfl_down(reg_c, off);
        pos_c += __shfl_down(pos_c, off);
    }
    __shared__ float    sc[4], sr[4];
    __shared__ unsigned sp[4];
    const int wave = tid >> 6, lane = tid & 63;
    if (lane == 0) { sc[wave] = cls_c; sr[wave] = reg_c; sp[wave] = pos_c; }
    __syncthreads();
    if (tid == 0) {
        const float    c = sc[0] + sc[1] + sc[2] + sc[3];
        const float    r = sr[0] + sr[1] + sr[2] + sr[3];
        const unsigned p = sp[0] + sp[1] + sp[2] + sp[3];
        atomicAdd(&ws[b * 4 + 0], c);
        atomicAdd(&ws[b * 4 + 1], r);
        atomicAdd(reinterpret_cast<unsigned*>(ws) + b * 4 + 2, p);
    }
}

__global__ __launch_bounds__(64) void focal_finalize(
    const float* __restrict__ ann_,
    const float* __restrict__ ws,
    float* __restrict__ out)
{
    __shared__ float s_cls[NB], s_reg[NB];
    const int b = threadIdx.x;
    if (b < NB) {
        int nv = 0;
        for (int m = 0; m < NM; ++m)
            if (ann_[(size_t)b * NM * 5 + m * 5 + 4] > -0.5f) nv++;
        const float    cls_sum = ws[b * 4 + 0];
        const float    reg_sum = ws[b * 4 + 1];
        const unsigned npos    = reinterpret_cast<const unsigned*>(ws)[b * 4 + 2];
        float cl = cls_sum / fmaxf((float)npos, 1.f);
        float rl = (npos > 0u) ? reg_sum / (float)(npos * 4u) : 0.f;
        if (nv == 0) { cl = 0.f; rl = 0.f; }
        s_cls[b] = cl;
        s_reg[b] = rl;
    }
    __syncthreads();
    if (threadIdx.x == 0) {
        float c = 0.f, r = 0.f;
        for (int i = 0; i < NB; ++i) { c += s_cls[i]; r += s_reg[i]; }
        out[0] = c * (1.f / NB);
        out[1] = r * (1.f / NB);
    }
}

extern "C" void kernel_launch(void* const* d_in, const int* in_sizes, int n_in,
                              void* d_out, int out_size, void* d_ws, size_t ws_size,
                              hipStream_t stream)
{
    const float* cls_  = (const float*)d_in[0];
    const float* reg_  = (const float*)d_in[1];
    const float* anch_ = (const float*)d_in[2];
    const float* ann_  = (const float*)d_in[3];
    float* ws  = (float*)d_ws;
    float* out = (float*)d_out;

    hipMemsetAsync(d_ws, 0, NB * 4 * sizeof(float), stream);

    dim3 grid((NA + 255) / 256, NB);
    focal_main<<<grid, dim3(256), 0, stream>>>(cls_, reg_, anch_, ann_, ws);
    focal_finalize<<<1, 64, 0, stream>>>(ann_, ws, out);
}

// Round 2
// 128.745 us; speedup vs baseline: 1.0147x; 1.0147x over previous
//
#include <hip/hip_runtime.h>

#define NB 16
#define NA 76725
#define NC 8
#define NM 32
#define FEPS 1e-4f

// ws layout (in floats):
//  [WS_ACC  .. +NB*4)  per-image accumulators: cls_sum, reg_sum, npos(uint), pad
//  [WS_CNT  .. +NB)    num_valid per image (float)
//  [WS_NVP  .. +NB)    padded valid count (multiple of 8) per image (float)
//  [WS_Q0   .. )       float4 per (b,m): {x1, y1, x2+1, y2+1}   (IoU loop data)
//  [WS_EPI  .. )       float4 per (b,m): {gcx, gcy, log(gw), log(gh)} (epilogue)
//  [WS_A2   .. )       float per (b,m): area2 (+1 convention)
//  [WS_LAB  .. )       float per (b,m): label
#define WS_ACC 0
#define WS_CNT (NB * 4)
#define WS_NVP (NB * 4 + NB)
#define WS_Q0  (NB * 4 + 2 * NB)                 // 96  -> byte 384, 16B aligned
#define WS_EPI (WS_Q0 + NB * NM * 4)             // 2144 -> byte 8576, 16B aligned
#define WS_A2  (WS_EPI + NB * NM * 4)            // 4192
#define WS_LAB (WS_A2 + NB * NM)                 // 4704
// total 5216 floats = 20864 bytes of ws

__global__ __launch_bounds__(64) void focal_prep(
    const float* __restrict__ ann_, float* __restrict__ ws)
{
    const int b = blockIdx.x;
    const int m = threadIdx.x;
    bool valid = false;
    float x1 = 0.f, y1 = 0.f, x2 = 0.f, y2 = 0.f, lab = -1.f;
    if (m < NM) {
        const float* r = ann_ + ((size_t)b * NM + m) * 5;
        x1 = r[0]; y1 = r[1]; x2 = r[2]; y2 = r[3]; lab = r[4];
        valid = lab > -0.5f;
        // sentinel record: inter==0, area2==1 -> never wins argmax (init ib=0,ub=1)
        reinterpret_cast<float4*>(ws + WS_Q0)[b * NM + m] =
            make_float4(3e18f, 3e18f, -3e18f, -3e18f);
        reinterpret_cast<float4*>(ws + WS_EPI)[b * NM + m] = make_float4(0.f, 0.f, 0.f, 0.f);
        ws[WS_A2 + b * NM + m] = 1.0f;
        ws[WS_LAB + b * NM + m] = -1.f;
    }
    const unsigned long long mask = __ballot(valid);
    const int cnt = __popcll(mask);
    __syncthreads();
    if (valid) {
        const int idx = __popcll(mask & ((1ull << m) - 1ull));  // stable compaction
        reinterpret_cast<float4*>(ws + WS_Q0)[b * NM + idx] =
            make_float4(x1, y1, x2 + 1.f, y2 + 1.f);
        const float w0 = x2 - x1, h0 = y2 - y1;
        reinterpret_cast<float4*>(ws + WS_EPI)[b * NM + idx] =
            make_float4(x1 + 0.5f * w0, y1 + 0.5f * h0,
                        __logf(fmaxf(w0, 1.f)), __logf(fmaxf(h0, 1.f)));
        ws[WS_A2 + b * NM + idx] = (x2 - x1 + 1.f) * (y2 - y1 + 1.f);
        ws[WS_LAB + b * NM + idx] = lab;
    }
    if (m == 0) {
        ws[WS_CNT + b] = (float)cnt;
        ws[WS_NVP + b] = (float)((cnt + 7) & ~7);
    }
}

__global__ __launch_bounds__(256) void focal_main(
    const float* __restrict__ cls_,
    const float* __restrict__ reg_,
    const float* __restrict__ anch_,
    float* __restrict__ ws)
{
    const int b = blockIdx.y;
    const int a = blockIdx.x * 256 + threadIdx.x;
    const int nvp = (int)ws[WS_NVP + b];  // uniform -> scalar load

    float cls_c = 0.f, reg_c = 0.f;
    unsigned pos_c = 0;

    if (a < NA) {
        const float4 an = *reinterpret_cast<const float4*>(anch_ + ((size_t)b * NA + a) * 4);
        const float ax = an.x, ay = an.y;
        const float az1 = an.z + 1.f, aw1 = an.w + 1.f;  // fold the +1 into the min
        const float area1 = (an.z - ax + 1.f) * (an.w - ay + 1.f);

        const float* q0a = ws + WS_Q0 + (size_t)b * NM * 4;  // uniform base
        const float* a2a = ws + WS_A2 + (size_t)b * NM;

        // running best as a ratio ib/ub (union > 0 always); division-free argmax
        float ib = 0.f, ub = 1.f;
        int arg = 0;
        #pragma unroll 8
        for (int m = 0; m < nvp; ++m) {
            const float4 q = *reinterpret_cast<const float4*>(q0a + 4 * m);  // s_load
            const float a2 = a2a[m];                                          // s_load
            const float w = fminf(az1, q.z) - fmaxf(ax, q.x);
            const float h = fminf(aw1, q.w) - fmaxf(ay, q.y);
            const float inter = fmaxf(w, 0.f) * fmaxf(h, 0.f);
            const float u = area1 + a2 - inter;
            const bool better = inter * ub > ib * u;   // strict > == first-occurrence
            ib = better ? inter : ib;
            ub = better ? u : ub;
            arg = better ? m : arg;
        }
        const bool pos = ib >= 0.4f * ub;
        const bool neg = ib < 0.3f * ub;

        int labi = -1;
        float4 ep = make_float4(0.f, 0.f, 0.f, 0.f);
        if (pos) {   // divergent, tiny L2-hot table
            ep = reinterpret_cast<const float4*>(ws + WS_EPI)[b * NM + arg];
            labi = (int)ws[WS_LAB + b * NM + arg];
        }

        if (pos || neg) {
            const float* cp = cls_ + ((size_t)b * NA + a) * NC;
            const float4 c0 = *reinterpret_cast<const float4*>(cp);
            const float4 c1 = *reinterpret_cast<const float4*>(cp + 4);
            const float pv[8] = {c0.x, c0.y, c0.z, c0.w, c1.x, c1.y, c1.z, c1.w};
            #pragma unroll
            for (int c = 0; c < NC; ++c) {
                const float p = fminf(fmaxf(pv[c], FEPS), 1.f - FEPS);
                const bool is_one = (c == labi);
                const float af = is_one ? 0.25f : 0.75f;
                const float pf = is_one ? (1.f - p) : p;
                const float bce = -__logf(is_one ? p : (1.f - p));
                cls_c += af * pf * pf * bce;
            }
        }
        if (pos) {
            pos_c = 1;
            const float awd = an.z - ax;   // no +1 for regression geometry
            const float ahd = an.w - ay;
            const float acx = ax + 0.5f * awd;
            const float acy = ay + 0.5f * ahd;
            const float t0 = __fdividef(ep.x - acx, awd) * 10.f;
            const float t1 = __fdividef(ep.y - acy, ahd) * 10.f;
            const float t2 = (ep.z - __logf(awd)) * 5.f;
            const float t3 = (ep.w - __logf(ahd)) * 5.f;
            const float4 rg = *reinterpret_cast<const float4*>(reg_ + ((size_t)b * NA + a) * 4);
            const float d0 = fabsf(t0 - rg.x);
            const float d1 = fabsf(t1 - rg.y);
            const float d2 = fabsf(t2 - rg.z);
            const float d3 = fabsf(t3 - rg.w);
            auto sl1 = [](float d) {
                return d <= (1.f / 9.f) ? 4.5f * d * d : d - (0.5f / 9.f);
            };
            reg_c = sl1(d0) + sl1(d1) + sl1(d2) + sl1(d3);
        }
    }

    // wave-64 shuffle reduction, cross-wave via LDS, 3 atomics per block
    #pragma unroll
    for (int off = 32; off > 0; off >>= 1) {
        cls_c += __shfl_down(cls_c, off);
        reg_c += __shfl_down(reg_c, off);
        pos_c += __shfl_down(pos_c, off);
    }
    __shared__ float    sc[4], sr[4];
    __shared__ unsigned sp[4];
    const int wave = threadIdx.x >> 6, lane = threadIdx.x & 63;
    if (lane == 0) { sc[wave] = cls_c; sr[wave] = reg_c; sp[wave] = pos_c; }
    __syncthreads();
    if (threadIdx.x == 0) {
        const float    c = sc[0] + sc[1] + sc[2] + sc[3];
        const float    r = sr[0] + sr[1] + sr[2] + sr[3];
        const unsigned p = sp[0] + sp[1] + sp[2] + sp[3];
        atomicAdd(&ws[WS_ACC + b * 4 + 0], c);
        atomicAdd(&ws[WS_ACC + b * 4 + 1], r);
        atomicAdd(reinterpret_cast<unsigned*>(ws) + WS_ACC + b * 4 + 2, p);
    }
}

__global__ __launch_bounds__(64) void focal_finalize(
    const float* __restrict__ ws, float* __restrict__ out)
{
    __shared__ float s_cls[NB], s_reg[NB];
    const int b = threadIdx.x;
    if (b < NB) {
        const float    nv      = ws[WS_CNT + b];
        const float    cls_sum = ws[WS_ACC + b * 4 + 0];
        const float    reg_sum = ws[WS_ACC + b * 4 + 1];
        const unsigned npos    = reinterpret_cast<const unsigned*>(ws)[WS_ACC + b * 4 + 2];
        float cl = cls_sum / fmaxf((float)npos, 1.f);
        float rl = (npos > 0u) ? reg_sum / (float)(npos * 4u) : 0.f;
        if (nv < 0.5f) { cl = 0.f; rl = 0.f; }
        s_cls[b] = cl;
        s_reg[b] = rl;
    }
    __syncthreads();
    if (threadIdx.x == 0) {
        float c = 0.f, r = 0.f;
        for (int i = 0; i < NB; ++i) { c += s_cls[i]; r += s_reg[i]; }
        out[0] = c * (1.f / NB);
        out[1] = r * (1.f / NB);
    }
}

extern "C" void kernel_launch(void* const* d_in, const int* in_sizes, int n_in,
                              void* d_out, int out_size, void* d_ws, size_t ws_size,
                              hipStream_t stream)
{
    const float* cls_  = (const float*)d_in[0];
    const float* reg_  = (const float*)d_in[1];
    const float* anch_ = (const float*)d_in[2];
    const float* ann_  = (const float*)d_in[3];
    float* ws  = (float*)d_ws;
    float* out = (float*)d_out;

    hipMemsetAsync(d_ws, 0, NB * 4 * sizeof(float), stream);

    focal_prep<<<NB, 64, 0, stream>>>(ann_, ws);
    dim3 grid((NA + 255) / 256, NB);
    focal_main<<<grid, dim3(256), 0, stream>>>(cls_, reg_, anch_, ws);
    focal_finalize<<<1, 64, 0, stream>>>(ws, out);
}

// Round 3
// 53.376 us; speedup vs baseline: 2.4474x; 2.4120x over previous
//
#include <hip/hip_runtime.h>

#define NB 16
#define NA 76725
#define NC 8
#define NM 32
#define FEPS 1e-4f
#define APT 4                     // anchors per thread
#define TPB 256
#define ANCH_PER_BLK (APT * TPB)  // 1024

// ws layout (in floats):
//  [WS_ACC .. +NB*4)  per-image accumulators: cls_sum, reg_sum, npos(uint), pad
//  [WS_CNT .. +NB)    num_valid per image (float)
//  [WS_NVP .. +NB)    padded valid count (multiple of 8) per image (float)
//  [WS_Q0  .. )       float4 per (b,m): {x1, y1, x2+1, y2+1}
//  [WS_EPI .. )       float4 per (b,m): {gcx, gcy, log(gw), log(gh)}
//  [WS_A2  .. )       float per (b,m): area2 (+1 convention)
//  [WS_LAB .. )       float per (b,m): label
#define WS_ACC 0
#define WS_CNT (NB * 4)
#define WS_NVP (NB * 4 + NB)
#define WS_Q0  (NB * 4 + 2 * NB)
#define WS_EPI (WS_Q0 + NB * NM * 4)
#define WS_A2  (WS_EPI + NB * NM * 4)
#define WS_LAB (WS_A2 + NB * NM)

__global__ __launch_bounds__(64) void focal_prep(
    const float* __restrict__ ann_, float* __restrict__ ws)
{
    const int b = blockIdx.x;
    const int m = threadIdx.x;
    bool valid = false;
    float x1 = 0.f, y1 = 0.f, x2 = 0.f, y2 = 0.f, lab = -1.f;
    if (m < NM) {
        const float* r = ann_ + ((size_t)b * NM + m) * 5;
        x1 = r[0]; y1 = r[1]; x2 = r[2]; y2 = r[3]; lab = r[4];
        valid = lab > -0.5f;
        // sentinel record: inter==0 -> never beats init (ib=0, ub=1)
        reinterpret_cast<float4*>(ws + WS_Q0)[b * NM + m] =
            make_float4(3e18f, 3e18f, -3e18f, -3e18f);
        reinterpret_cast<float4*>(ws + WS_EPI)[b * NM + m] = make_float4(0.f, 0.f, 0.f, 0.f);
        ws[WS_A2 + b * NM + m] = 1.0f;
        ws[WS_LAB + b * NM + m] = -1.f;
    }
    const unsigned long long mask = __ballot(valid);
    const int cnt = __popcll(mask);
    __syncthreads();
    if (valid) {
        const int idx = __popcll(mask & ((1ull << m) - 1ull));  // stable compaction
        reinterpret_cast<float4*>(ws + WS_Q0)[b * NM + idx] =
            make_float4(x1, y1, x2 + 1.f, y2 + 1.f);
        const float w0 = x2 - x1, h0 = y2 - y1;
        reinterpret_cast<float4*>(ws + WS_EPI)[b * NM + idx] =
            make_float4(x1 + 0.5f * w0, y1 + 0.5f * h0,
                        __logf(fmaxf(w0, 1.f)), __logf(fmaxf(h0, 1.f)));
        ws[WS_A2 + b * NM + idx] = (x2 - x1 + 1.f) * (y2 - y1 + 1.f);
        ws[WS_LAB + b * NM + idx] = lab;
    }
    if (m == 0) {
        ws[WS_CNT + b] = (float)cnt;
        ws[WS_NVP + b] = (float)((cnt + 7) & ~7);
    }
}

__global__ __launch_bounds__(TPB, 4) void focal_main(
    const float* __restrict__ cls_,
    const float* __restrict__ reg_,
    const float* __restrict__ anch_,
    float* __restrict__ ws)
{
    const int b   = blockIdx.y;
    const int tid = threadIdx.x;

    __shared__ float  s_x1[NM], s_y1[NM], s_x21[NM], s_y21[NM], s_a2[NM];
    __shared__ float4 s_epi[NM];
    __shared__ float  s_lab[NM];

    if (tid < NM) {
        const float4 q = reinterpret_cast<const float4*>(ws + WS_Q0)[b * NM + tid];
        s_x1[tid] = q.x; s_y1[tid] = q.y; s_x21[tid] = q.z; s_y21[tid] = q.w;
        s_a2[tid]  = ws[WS_A2 + b * NM + tid];
        s_epi[tid] = reinterpret_cast<const float4*>(ws + WS_EPI)[b * NM + tid];
        s_lab[tid] = ws[WS_LAB + b * NM + tid];
    }
    int nvp = (int)ws[WS_NVP + b];
    nvp = __builtin_amdgcn_readfirstlane(nvp);   // wave-uniform -> scalar loop
    __syncthreads();

    const int a0 = blockIdx.x * ANCH_PER_BLK + tid;

    // ---- issue ALL global loads up front (independent, 16x dwordx4 in flight)
    bool   amask[APT];
    float4 an[APT], rg[APT], cv0[APT], cv1[APT];
    #pragma unroll
    for (int k = 0; k < APT; ++k) {
        const int a = a0 + k * TPB;
        amask[k] = (a < NA);
        const int ac = amask[k] ? a : (NA - 1);        // clamp, mask later
        const size_t base = (size_t)b * NA + ac;
        an[k]  = reinterpret_cast<const float4*>(anch_)[base];
        rg[k]  = reinterpret_cast<const float4*>(reg_)[base];
        cv0[k] = reinterpret_cast<const float4*>(cls_)[base * 2];
        cv1[k] = reinterpret_cast<const float4*>(cls_)[base * 2 + 1];
    }

    // ---- per-anchor IoU-argmax state (division-free, ratio as ib/ub)
    float ax[APT], ay[APT], az1[APT], aw1[APT], area1[APT];
    float ib[APT], ub[APT];
    int   arg[APT];
    #pragma unroll
    for (int k = 0; k < APT; ++k) {
        ax[k]  = an[k].x; ay[k] = an[k].y;
        az1[k] = an[k].z + 1.f; aw1[k] = an[k].w + 1.f;
        area1[k] = (an[k].z - ax[k] + 1.f) * (an[k].w - ay[k] + 1.f);
        ib[k] = 0.f; ub[k] = 1.f; arg[k] = 0;
    }

    #pragma unroll 4
    for (int m = 0; m < nvp; ++m) {
        const float x1 = s_x1[m], y1 = s_y1[m];        // LDS broadcast reads
        const float x21 = s_x21[m], y21 = s_y21[m];
        const float a2 = s_a2[m];
        #pragma unroll
        for (int k = 0; k < APT; ++k) {
            const float w = fminf(az1[k], x21) - fmaxf(ax[k], x1);
            const float h = fminf(aw1[k], y21) - fmaxf(ay[k], y1);
            const float inter = fmaxf(w, 0.f) * fmaxf(h, 0.f);
            const float u = area1[k] + a2 - inter;
            const bool better = inter * ub[k] > ib[k] * u;  // strict >: first-occurrence
            ib[k]  = better ? inter : ib[k];
            ub[k]  = better ? u : ub[k];
            arg[k] = better ? m : arg[k];
        }
    }

    float cls_c = 0.f, reg_c = 0.f;
    unsigned pos_c = 0;

    #pragma unroll
    for (int k = 0; k < APT; ++k) {
        const bool pos = ib[k] >= 0.4f * ub[k];
        const bool neg = ib[k] <  0.3f * ub[k];
        const bool act = (pos || neg) && amask[k];

        // base: all 8 classes with the "negative" formula (8 independent chains)
        float pcl[8];
        {
            const float pv[8] = {cv0[k].x, cv0[k].y, cv0[k].z, cv0[k].w,
                                 cv1[k].x, cv1[k].y, cv1[k].z, cv1[k].w};
            float bsum = 0.f;
            #pragma unroll
            for (int c = 0; c < NC; ++c) {
                const float p = fminf(fmaxf(pv[c], FEPS), 1.f - FEPS);
                pcl[c] = p;
                bsum += 0.75f * p * p * (-__logf(1.f - p));
            }
            float contrib = bsum;
            if (pos) {
                const int labi = (int)s_lab[arg[k]];
                // select p[labi] with a 7-cndmask tree (static indices only)
                const float t0 = (labi & 1) ? pcl[1] : pcl[0];
                const float t1 = (labi & 1) ? pcl[3] : pcl[2];
                const float t2 = (labi & 1) ? pcl[5] : pcl[4];
                const float t3 = (labi & 1) ? pcl[7] : pcl[6];
                const float u0 = (labi & 2) ? t1 : t0;
                const float u1 = (labi & 2) ? t3 : t2;
                const float pt = (labi & 4) ? u1 : u0;
                const float om = 1.f - pt;
                contrib += 0.25f * om * om * (-__logf(pt))
                         - 0.75f * pt * pt * (-__logf(om));
            }
            cls_c += act ? contrib : 0.f;
        }

        if (pos && amask[k]) {
            pos_c += 1;
            const float4 ep = s_epi[arg[k]];
            const float awd = az1[k] - 1.f - ax[k];    // no +1 for regression geometry
            const float ahd = aw1[k] - 1.f - ay[k];
            const float acx = ax[k] + 0.5f * awd;
            const float acy = ay[k] + 0.5f * ahd;
            const float t0 = __fdividef(ep.x - acx, awd) * 10.f;
            const float t1 = __fdividef(ep.y - acy, ahd) * 10.f;
            const float t2 = (ep.z - __logf(awd)) * 5.f;
            const float t3 = (ep.w - __logf(ahd)) * 5.f;
            const float d0 = fabsf(t0 - rg[k].x);
            const float d1 = fabsf(t1 - rg[k].y);
            const float d2 = fabsf(t2 - rg[k].z);
            const float d3 = fabsf(t3 - rg[k].w);
            auto sl1 = [](float d) {
                return d <= (1.f / 9.f) ? 4.5f * d * d : d - (0.5f / 9.f);
            };
            reg_c += sl1(d0) + sl1(d1) + sl1(d2) + sl1(d3);
        }
    }

    // wave-64 shuffle reduction, cross-wave via LDS, 3 atomics per block
    #pragma unroll
    for (int off = 32; off > 0; off >>= 1) {
        cls_c += __shfl_down(cls_c, off);
        reg_c += __shfl_down(reg_c, off);
        pos_c += __shfl_down(pos_c, off);
    }
    __shared__ float    sc[4], sr[4];
    __shared__ unsigned sp[4];
    const int wave = tid >> 6, lane = tid & 63;
    if (lane == 0) { sc[wave] = cls_c; sr[wave] = reg_c; sp[wave] = pos_c; }
    __syncthreads();
    if (tid == 0) {
        const float    c = sc[0] + sc[1] + sc[2] + sc[3];
        const float    r = sr[0] + sr[1] + sr[2] + sr[3];
        const unsigned p = sp[0] + sp[1] + sp[2] + sp[3];
        atomicAdd(&ws[WS_ACC + b * 4 + 0], c);
        atomicAdd(&ws[WS_ACC + b * 4 + 1], r);
        atomicAdd(reinterpret_cast<unsigned*>(ws) + WS_ACC + b * 4 + 2, p);
    }
}

__global__ __launch_bounds__(64) void focal_finalize(
    const float* __restrict__ ws, float* __restrict__ out)
{
    __shared__ float s_cls[NB], s_reg[NB];
    const int b = threadIdx.x;
    if (b < NB) {
        const float    nv      = ws[WS_CNT + b];
        const float    cls_sum = ws[WS_ACC + b * 4 + 0];
        const float    reg_sum = ws[WS_ACC + b * 4 + 1];
        const unsigned npos    = reinterpret_cast<const unsigned*>(ws)[WS_ACC + b * 4 + 2];
        float cl = cls_sum / fmaxf((float)npos, 1.f);
        float rl = (npos > 0u) ? reg_sum / (float)(npos * 4u) : 0.f;
        if (nv < 0.5f) { cl = 0.f; rl = 0.f; }
        s_cls[b] = cl;
        s_reg[b] = rl;
    }
    __syncthreads();
    if (threadIdx.x == 0) {
        float c = 0.f, r = 0.f;
        for (int i = 0; i < NB; ++i) { c += s_cls[i]; r += s_reg[i]; }
        out[0] = c * (1.f / NB);
        out[1] = r * (1.f / NB);
    }
}

extern "C" void kernel_launch(void* const* d_in, const int* in_sizes, int n_in,
                              void* d_out, int out_size, void* d_ws, size_t ws_size,
                              hipStream_t stream)
{
    const float* cls_  = (const float*)d_in[0];
    const float* reg_  = (const float*)d_in[1];
    const float* anch_ = (const float*)d_in[2];
    const float* ann_  = (const float*)d_in[3];
    float* ws  = (float*)d_ws;
    float* out = (float*)d_out;

    hipMemsetAsync(d_ws, 0, NB * 4 * sizeof(float), stream);

    focal_prep<<<NB, 64, 0, stream>>>(ann_, ws);
    dim3 grid((NA + ANCH_PER_BLK - 1) / ANCH_PER_BLK, NB);
    focal_main<<<grid, dim3(TPB), 0, stream>>>(cls_, reg_, anch_, ws);
    focal_finalize<<<1, 64, 0, stream>>>(ws, out);
}